// Round 1
// baseline (258.548 us; speedup 1.0000x reference)
//
#include <hip/hip_runtime.h>
#include <hip/hip_bf16.h>

// RBF: out[n, i, 0] = exp(-||x_cur[n]     - c_i||^2 / beta)
//      out[n, i, 1] = exp(-||x_delayed[n] - c_i||^2 / beta)
// N_STEPS=8192, OUT_FEATURES=4096, IN_FEATURES=2, beta=0.04.
// Output: 8192*4096*2 float32 = 256 MB -> write-BW-bound (~41 us floor).

#define N_STEPS      8192
#define OUT_FEATURES 4096

__global__ __launch_bounds__(256) void
RBF_36404142801269_kernel(const float* __restrict__ x_cur,
                          const float* __restrict__ x_delayed,
                          const float* __restrict__ centres,
                          float* __restrict__ out) {
    const int n = blockIdx.x;  // one block per timestep row

    // Per-row query points (wave-uniform; scalar loads after readfirstlane).
    const float xc0 = x_cur[n * 2 + 0];
    const float xc1 = x_cur[n * 2 + 1];
    const float xd0 = x_delayed[n * 2 + 0];
    const float xd1 = x_delayed[n * 2 + 1];

    // exp(-d2/beta) = exp2(d2 * COEF), COEF = -log2(e)/beta
    const float COEF = -1.44269504088896f / 0.04f;

    const float4* __restrict__ cv = (const float4*)centres;          // 2048 x (2 centres)
    float4* __restrict__ ov = (float4*)(out + (size_t)n * OUT_FEATURES * 2);

    // 2048 float4 outputs per row; 256 threads -> 8 iterations each.
    for (int j = threadIdx.x; j < OUT_FEATURES / 2; j += 256) {
        const float4 c = cv[j];  // centre A=(c.x,c.y), centre B=(c.z,c.w)

        // centre A
        float a0 = xc0 - c.x, a1 = xc1 - c.y;
        float sA_now = a0 * a0 + a1 * a1;
        a0 = xd0 - c.x; a1 = xd1 - c.y;
        float sA_del = a0 * a0 + a1 * a1;

        // centre B
        float b0 = xc0 - c.z, b1 = xc1 - c.w;
        float sB_now = b0 * b0 + b1 * b1;
        b0 = xd0 - c.z; b1 = xd1 - c.w;
        float sB_del = b0 * b0 + b1 * b1;

        float4 o;
        o.x = exp2f(sA_now * COEF);  // k_now(2j)
        o.y = exp2f(sA_del * COEF);  // k_del(2j)
        o.z = exp2f(sB_now * COEF);  // k_now(2j+1)
        o.w = exp2f(sB_del * COEF);  // k_del(2j+1)
        ov[j] = o;
    }
}

extern "C" void kernel_launch(void* const* d_in, const int* in_sizes, int n_in,
                              void* d_out, int out_size, void* d_ws, size_t ws_size,
                              hipStream_t stream) {
    const float* x_cur     = (const float*)d_in[0];
    const float* x_delayed = (const float*)d_in[1];
    const float* centres   = (const float*)d_in[2];
    float* out             = (float*)d_out;

    RBF_36404142801269_kernel<<<N_STEPS, 256, 0, stream>>>(x_cur, x_delayed, centres, out);
}